// Round 7
// baseline (856.531 us; speedup 1.0000x reference)
//
#include <hip/hip_runtime.h>
#include <math.h>

#define N_NODES 50000
#define E_ORIG  800000
#define E_TOT   850000   // + self loops
#define SNB     49       // scan blocks: 49 * 1024 >= N_NODES
#define BPG     1563     // gather blocks per slice-phase: 1563 * 32 >= N_NODES

typedef __attribute__((ext_vector_type(8))) short short8;   // 8 bf16 (4 VGPRs)
typedef __attribute__((ext_vector_type(4))) float f32x4;    // MFMA acc

__device__ __forceinline__ short f2bf(float f) {            // fp32 -> bf16 RNE
    unsigned u = __builtin_bit_cast(unsigned, f);
    u += 0x7FFFu + ((u >> 16) & 1u);
    return (short)(u >> 16);
}
__device__ __forceinline__ float bf2f(short s) {
    unsigned u = ((unsigned)(unsigned short)s) << 16;
    return __builtin_bit_cast(float, u);
}

// ---------------- bf16 MFMA GEMM: C_t[blk][m][32] = (A[M,K] @ W[K,N]) sliced ----------------
// 128x64 tile (many blocks: these GEMMs are thin/tail-bound), BK=32, 4 waves = 2x2 of 64x32.
__global__ __launch_bounds__(256) void gemm_bf16(const short* __restrict__ A,
                                                 const short* __restrict__ Wt,   // W^T [N][K]
                                                 short* __restrict__ C,          // [N/32][N_NODES][32]
                                                 int M, int N, int K)
{
    __shared__ short sA[128][40];
    __shared__ short sB[64][40];
    const int t    = threadIdx.x;
    const int wave = t >> 6, lane = t & 63;
    const int quad = lane >> 4, mrow = lane & 15;
    const int m0 = blockIdx.y * 128, n0 = blockIdx.x * 64;
    const int wm = (wave & 1) * 64, wn = (wave >> 1) * 32;

    f32x4 acc[4][2] = {};

    const int ra = t >> 2, ka = (t & 3) << 3;   // A: 2 passes of 64 rows, 8 shorts each
    const int rb = t >> 2, kb = (t & 3) << 3;   // B: 64 rows, 8 shorts each

    for (int k0 = 0; k0 < K; k0 += 32) {
#pragma unroll
        for (int rr = 0; rr < 2; ++rr) {
            int row = ra + rr * 64;
            int gm = m0 + row;
            int4 v = {0, 0, 0, 0};
            if (gm < M) v = *(const int4*)(A + (size_t)gm * K + k0 + ka);
            *(int4*)&sA[row][ka] = v;
        }
        {
            int4 v = *(const int4*)(Wt + (size_t)(n0 + rb) * K + k0 + kb);
            *(int4*)&sB[rb][kb] = v;
        }
        __syncthreads();
        short8 af[4], bfr[2];
#pragma unroll
        for (int mi = 0; mi < 4; ++mi)
            af[mi] = *(const short8*)&sA[wm + mi * 16 + mrow][quad * 8];
#pragma unroll
        for (int ni = 0; ni < 2; ++ni)
            bfr[ni] = *(const short8*)&sB[wn + ni * 16 + mrow][quad * 8];
#pragma unroll
        for (int mi = 0; mi < 4; ++mi)
#pragma unroll
            for (int ni = 0; ni < 2; ++ni)
                acc[mi][ni] = __builtin_amdgcn_mfma_f32_16x16x32_bf16(af[mi], bfr[ni], acc[mi][ni], 0, 0, 0);
        __syncthreads();
    }
    // C/D layout: col = lane&15, row = quad*4 + reg; write slice-major
#pragma unroll
    for (int mi = 0; mi < 4; ++mi) {
#pragma unroll
        for (int ni = 0; ni < 2; ++ni) {
            int gn = n0 + wn + ni * 16 + mrow;
            size_t sbase = ((size_t)(gn >> 5) * N_NODES) * 32 + (gn & 31);
            int gmb = m0 + wm + mi * 16 + quad * 4;
#pragma unroll
            for (int r = 0; r < 4; ++r) {
                int gm = gmb + r;
                if (gm < M) C[sbase + (size_t)gm * 32] = f2bf(acc[mi][ni][r]);
            }
        }
    }
}

// ---------------- casts ----------------
__global__ void xcast_kernel(const float* __restrict__ x, short* __restrict__ xb, int total4)
{
    int i = blockIdx.x * blockDim.x + threadIdx.x;
    if (i >= total4) return;
    float4 v = ((const float4*)x)[i];
    short4 o; o.x = f2bf(v.x); o.y = f2bf(v.y); o.z = f2bf(v.z); o.w = f2bf(v.w);
    ((short4*)xb)[i] = o;
}

__global__ void wtcast_all(const float* __restrict__ W1, const float* __restrict__ W2,
                           const float* __restrict__ W3, short* __restrict__ wt)
{
    int i = blockIdx.x * blockDim.x + threadIdx.x;
    if (i < 32768) {                       // W1: K=128, N=256
        int n = i / 128, k = i % 128;
        wt[i] = f2bf(W1[(size_t)k * 256 + n]);
    } else if (i < 98304) {                // W2: K=256, N=256
        int j = i - 32768;
        int n = j / 256, k = j % 256;
        wt[i] = f2bf(W2[(size_t)k * 256 + n]);
    } else if (i < 131072) {               // W3: K=256, N=128
        int j = i - 98304;
        int n = j / 256, k = j % 256;
        wt[i] = f2bf(W3[(size_t)k * 128 + n]);
    }
}

// ---------------- attention logits, head-major outputs: al[h][n] ----------------
template<int H, int BPH>
__global__ void logits_blk(const short* __restrict__ ht,
                           const float* __restrict__ a_src,
                           const float* __restrict__ a_dst,
                           float* __restrict__ al_s, float* __restrict__ al_d)
{
    int i = blockIdx.x * blockDim.x + threadIdx.x;
    if (i >= N_NODES * H) return;
    int n = i / H, hh = i % H;
    float ss = 0.f, sd = 0.f;
#pragma unroll
    for (int b = 0; b < BPH; ++b) {
        int blk = hh * BPH + b;
        const short* hp = ht + ((size_t)blk * N_NODES + n) * 32;
        const float* as = a_src + blk * 32;
        const float* ad = a_dst + blk * 32;
#pragma unroll
        for (int c8 = 0; c8 < 32; c8 += 8) {
            short8 hv = *(const short8*)(hp + c8);
#pragma unroll
            for (int j = 0; j < 8; ++j) {
                float v = bf2f(hv[j]);
                ss = fmaf(v, as[c8 + j], ss);
                sd = fmaf(v, ad[c8 + j], sd);
            }
        }
    }
    al_s[(size_t)hh * N_NODES + n] = ss;
    al_d[(size_t)hh * N_NODES + n] = sd;
}

// ---------------- CSR build ----------------
__global__ void deg_kernel(const int* __restrict__ ei, int* __restrict__ deg)
{
    int e = blockIdx.x * blockDim.x + threadIdx.x;
    if (e >= E_TOT) return;
    int d = (e < E_ORIG) ? ei[E_ORIG + e] : e - E_ORIG;
    atomicAdd(&deg[d], 1);
}

__global__ __launch_bounds__(256) void scan_p1(const int* __restrict__ deg, int* __restrict__ bsum)
{
    __shared__ int wsum[4];
    int t = threadIdx.x;
    int base = blockIdx.x * 1024 + t * 4;
    int s = 0;
    if (base + 3 < N_NODES) {
        int4 v = *(const int4*)(deg + base);
        s = v.x + v.y + v.z + v.w;
    } else if (base < N_NODES) {
        for (int j = 0; j < 4 && base + j < N_NODES; ++j) s += deg[base + j];
    }
#pragma unroll
    for (int d = 32; d; d >>= 1) s += __shfl_down(s, d);
    if ((t & 63) == 0) wsum[t >> 6] = s;
    __syncthreads();
    if (t == 0) bsum[blockIdx.x] = wsum[0] + wsum[1] + wsum[2] + wsum[3];
}

__global__ void scan_p2(const int* __restrict__ bsum, int* __restrict__ bpre,
                        int* __restrict__ row_ptr)
{
    int t = threadIdx.x;   // 64 threads
    int v = (t < SNB) ? bsum[t] : 0;
    int inc = v;
#pragma unroll
    for (int d = 1; d < 64; d <<= 1) {
        int u = __shfl_up(inc, d);
        if (t >= d) inc += u;
    }
    if (t < SNB) bpre[t] = inc - v;
    if (t == SNB - 1) row_ptr[N_NODES] = inc;
}

__global__ __launch_bounds__(256) void scan_p3(const int* __restrict__ deg,
                                               const int* __restrict__ bpre,
                                               int* __restrict__ row_ptr,
                                               int* __restrict__ cursor)
{
    __shared__ int tsum[256];
    int t = threadIdx.x;
    int base = blockIdx.x * 1024 + t * 4;
    int d0 = 0, d1 = 0, d2 = 0, d3 = 0;
    if (base + 3 < N_NODES) {
        int4 v = *(const int4*)(deg + base);
        d0 = v.x; d1 = v.y; d2 = v.z; d3 = v.w;
    } else if (base < N_NODES) {
        d0 = deg[base];
        if (base + 1 < N_NODES) d1 = deg[base + 1];
        if (base + 2 < N_NODES) d2 = deg[base + 2];
    }
    int s = d0 + d1 + d2 + d3;
    tsum[t] = s;
    __syncthreads();
    for (int off = 1; off < 256; off <<= 1) {
        int u = (t >= off) ? tsum[t - off] : 0;
        __syncthreads();
        tsum[t] += u;
        __syncthreads();
    }
    int run = bpre[blockIdx.x] + tsum[t] - s;
    if (base < N_NODES)     { row_ptr[base]     = run; cursor[base]     = run; run += d0; }
    if (base + 1 < N_NODES) { row_ptr[base + 1] = run; cursor[base + 1] = run; run += d1; }
    if (base + 2 < N_NODES) { row_ptr[base + 2] = run; cursor[base + 2] = run; run += d2; }
    if (base + 3 < N_NODES) { row_ptr[base + 3] = run; cursor[base + 3] = run; }
}

__global__ void fill_kernel(const int* __restrict__ ei, int* __restrict__ cursor,
                            int* __restrict__ col)
{
    int e = blockIdx.x * blockDim.x + threadIdx.x;
    if (e >= E_TOT) return;
    int s, d;
    if (e < E_ORIG) { s = ei[e]; d = ei[E_ORIG + e]; } else { s = d = e - E_ORIG; }
    int pos = atomicAdd(&cursor[d], 1);
    col[pos] = s;
}

// ---------------- degree counting sort -> perm (waves get equal-degree nodes) ----------------
__global__ void hist_kernel(const int* __restrict__ deg, int* __restrict__ hist)
{
    int n = blockIdx.x * blockDim.x + threadIdx.x;
    if (n >= N_NODES) return;
    int d = deg[n]; if (d > 255) d = 255;
    atomicAdd(&hist[d], 1);
}

__global__ __launch_bounds__(256) void hist_scan(const int* __restrict__ hist, int* __restrict__ hcur)
{
    __shared__ int s[256];
    int t = threadIdx.x;
    int v = hist[t];
    s[t] = v;
    __syncthreads();
    for (int off = 1; off < 256; off <<= 1) {
        int u = (t >= off) ? s[t - off] : 0;
        __syncthreads();
        s[t] += u;
        __syncthreads();
    }
    hcur[t] = s[t] - v;   // exclusive
}

__global__ void perm_kernel(const int* __restrict__ deg, int* __restrict__ hcur,
                            int* __restrict__ perm)
{
    int n = blockIdx.x * blockDim.x + threadIdx.x;
    if (n >= N_NODES) return;
    int d = deg[n]; if (d > 255) d = 255;
    int pos = atomicAdd(&hcur[d], 1);
    perm[pos] = n;
}

// ---------------- slice-blocked gather with fused softmax weight ----------------
// grid = NBLK slice-phases x BPG blocks; block = 32 degree-sorted nodes x 8 lanes.
// w = exp(leaky(al_s[s]+al_d[n])) computed inline (each (e,head) used by exactly one phase
// for layers 1/2; recomputed 4x for layer 3 - cheaper than a w-buffer round trip).
template<int HC, int H, bool BN, bool OUTBF>
__global__ __launch_bounds__(256) void gat_gather_blk(const int* __restrict__ row_ptr,
                                                      const int* __restrict__ col,
                                                      const int* __restrict__ perm,
                                                      const short* __restrict__ ht,
                                                      const float* __restrict__ al_s,
                                                      const float* __restrict__ al_d,
                                                      const float* __restrict__ bias,
                                                      const float* __restrict__ gamma,
                                                      const float* __restrict__ beta,
                                                      const float* __restrict__ mean,
                                                      const float* __restrict__ var,
                                                      void* __restrict__ outp)
{
    constexpr int NBLK = HC / 32;
    int blk  = blockIdx.x / BPG;
    int nb   = blockIdx.x % BPG;
    int slot = nb * 32 + (threadIdx.x >> 3);
    if (slot >= N_NODES) return;
    int n = perm[slot];
    int lane  = threadIdx.x & 7;
    int head  = (blk * H) / NBLK;
    int c_loc = lane * 4;
    const short* hb  = ht + (size_t)blk * N_NODES * 32 + c_loc;
    const float* als = al_s + (size_t)head * N_NODES;
    float aldn = al_d[(size_t)head * N_NODES + n];
    int beg = row_ptr[n], end = row_ptr[n + 1];
    float a0 = 0.f, a1 = 0.f, a2 = 0.f, a3 = 0.f, den = 0.f;
    int e = beg;
#define MKW(si, wi) { float v = als[si] + aldn; v = v > 0.f ? v : 0.2f * v; wi = __expf(v); }
    for (; e + 3 < end; e += 4) {
        int s0 = col[e], s1 = col[e + 1], s2 = col[e + 2], s3 = col[e + 3];
        float w0, w1, w2, w3;
        MKW(s0, w0); MKW(s1, w1); MKW(s2, w2); MKW(s3, w3);
        short4 h0 = *(const short4*)(hb + (size_t)s0 * 32);
        short4 h1 = *(const short4*)(hb + (size_t)s1 * 32);
        short4 h2 = *(const short4*)(hb + (size_t)s2 * 32);
        short4 h3 = *(const short4*)(hb + (size_t)s3 * 32);
        den += (w0 + w1) + (w2 + w3);
        a0 = fmaf(w0, bf2f(h0.x), a0); a1 = fmaf(w0, bf2f(h0.y), a1);
        a2 = fmaf(w0, bf2f(h0.z), a2); a3 = fmaf(w0, bf2f(h0.w), a3);
        a0 = fmaf(w1, bf2f(h1.x), a0); a1 = fmaf(w1, bf2f(h1.y), a1);
        a2 = fmaf(w1, bf2f(h1.z), a2); a3 = fmaf(w1, bf2f(h1.w), a3);
        a0 = fmaf(w2, bf2f(h2.x), a0); a1 = fmaf(w2, bf2f(h2.y), a1);
        a2 = fmaf(w2, bf2f(h2.z), a2); a3 = fmaf(w2, bf2f(h2.w), a3);
        a0 = fmaf(w3, bf2f(h3.x), a0); a1 = fmaf(w3, bf2f(h3.y), a1);
        a2 = fmaf(w3, bf2f(h3.z), a2); a3 = fmaf(w3, bf2f(h3.w), a3);
    }
    for (; e < end; ++e) {
        int s0 = col[e];
        float w0; MKW(s0, w0);
        short4 h0 = *(const short4*)(hb + (size_t)s0 * 32);
        den += w0;
        a0 = fmaf(w0, bf2f(h0.x), a0); a1 = fmaf(w0, bf2f(h0.y), a1);
        a2 = fmaf(w0, bf2f(h0.z), a2); a3 = fmaf(w0, bf2f(h0.w), a3);
    }
#undef MKW
    float inv = 1.f / den;
    float r[4] = { a0 * inv, a1 * inv, a2 * inv, a3 * inv };
    int cb = blk * 32 + c_loc;
#pragma unroll
    for (int j = 0; j < 4; ++j) {
        int c = cb + j;
        float v = r[j] + bias[c];
        if (BN) {
            v = (v - mean[c]) * rsqrtf(var[c] + 1e-5f) * gamma[c] + beta[c];
            v = v > 0.f ? v : expm1f(v);   // ELU
        }
        r[j] = v;
    }
    if (OUTBF) {
        short4 o; o.x = f2bf(r[0]); o.y = f2bf(r[1]); o.z = f2bf(r[2]); o.w = f2bf(r[3]);
        *(short4*)((short*)outp + (size_t)n * HC + cb) = o;
    } else {
        *(float4*)((float*)outp + (size_t)n * HC + cb) = make_float4(r[0], r[1], r[2], r[3]);
    }
}

extern "C" void kernel_launch(void* const* d_in, const int* in_sizes, int n_in,
                              void* d_out, int out_size, void* d_ws, size_t ws_size,
                              hipStream_t stream)
{
    const float* x   = (const float*)d_in[0];
    const int*   ei  = (const int*)d_in[1];
    const float* W1  = (const float*)d_in[2];
    const float* as1 = (const float*)d_in[3];
    const float* ad1 = (const float*)d_in[4];
    const float* b1  = (const float*)d_in[5];
    const float* g1  = (const float*)d_in[6];
    const float* be1 = (const float*)d_in[7];
    const float* mn1 = (const float*)d_in[8];
    const float* vr1 = (const float*)d_in[9];
    const float* W2  = (const float*)d_in[10];
    const float* as2 = (const float*)d_in[11];
    const float* ad2 = (const float*)d_in[12];
    const float* b2  = (const float*)d_in[13];
    const float* g2  = (const float*)d_in[14];
    const float* be2 = (const float*)d_in[15];
    const float* mn2 = (const float*)d_in[16];
    const float* vr2 = (const float*)d_in[17];
    const float* W3  = (const float*)d_in[18];
    const float* as3 = (const float*)d_in[19];
    const float* ad3 = (const float*)d_in[20];
    const float* b3  = (const float*)d_in[21];

    char* p = (char*)d_ws;
    short* hbuf    = (short*)p; p += (size_t)N_NODES * 256 * 2;     // 25.6 MB (slice-major h)
    short* obuf    = (short*)p; p += (size_t)N_NODES * 256 * 2;     // 25.6 MB (row-major layer out)
    short* xbf     = (short*)p; p += (size_t)N_NODES * 128 * 2;     // 12.8 MB (bf16 x)
    short* wtbuf   = (short*)p; p += (size_t)131072 * 2;            // 256 KB (wt1|wt2|wt3)
    float* als     = (float*)p; p += (size_t)N_NODES * 8 * 4;       // head-major [h][n]
    float* ald     = (float*)p; p += (size_t)N_NODES * 8 * 4;
    int*   row_ptr = (int*)p;   p += (size_t)(N_NODES + 1) * 4;
    int*   col     = (int*)p;   p += (size_t)E_TOT * 4;
    int*   deg     = (int*)p;   p += (size_t)N_NODES * 4;
    int*   hist    = (int*)p;   p += 256 * 4;                       // contiguous after deg: one memset
    int*   cursor  = (int*)p;   p += (size_t)N_NODES * 4;
    int*   perm    = (int*)p;   p += (size_t)N_NODES * 4;
    int*   hcur    = (int*)p;   p += 256 * 4;
    int*   bsum    = (int*)p;   p += 64 * 4;
    int*   bpre    = (int*)p;   p += 64 * 4;

    short* wt1 = wtbuf;           // [256][128]
    short* wt2 = wtbuf + 32768;   // [256][256]
    short* wt3 = wtbuf + 98304;   // [128][256]

    float* out = (float*)d_out;

    // ----- CSR build + degree sort + upfront casts -----
    hipMemsetAsync(deg, 0, ((size_t)N_NODES + 256) * 4, stream);    // deg + hist
    deg_kernel<<<(E_TOT + 255) / 256, 256, 0, stream>>>(ei, deg);
    scan_p1<<<SNB, 256, 0, stream>>>(deg, bsum);
    scan_p2<<<1, 64, 0, stream>>>(bsum, bpre, row_ptr);
    scan_p3<<<SNB, 256, 0, stream>>>(deg, bpre, row_ptr, cursor);
    fill_kernel<<<(E_TOT + 255) / 256, 256, 0, stream>>>(ei, cursor, col);
    hist_kernel<<<(N_NODES + 255) / 256, 256, 0, stream>>>(deg, hist);
    hist_scan<<<1, 256, 0, stream>>>(hist, hcur);
    perm_kernel<<<(N_NODES + 255) / 256, 256, 0, stream>>>(deg, hcur, perm);
    xcast_kernel<<<(N_NODES * 128 / 4 + 255) / 256, 256, 0, stream>>>(x, xbf, N_NODES * 128 / 4);
    wtcast_all<<<(131072 + 255) / 256, 256, 0, stream>>>(W1, W2, W3, wtbuf);

    const int nh8 = N_NODES * 8;

    // ----- layer 1: GAT(128 -> 8x32) + BN + ELU -----
    gemm_bf16<<<dim3(4, (N_NODES + 127) / 128), 256, 0, stream>>>(xbf, wt1, hbuf, N_NODES, 256, 128);
    logits_blk<8, 1><<<(nh8 + 255) / 256, 256, 0, stream>>>(hbuf, as1, ad1, als, ald);
    gat_gather_blk<256, 8, true, true><<<BPG * 8, 256, 0, stream>>>(
        row_ptr, col, perm, hbuf, als, ald, b1, g1, be1, mn1, vr1, obuf);

    // ----- layer 2: GAT(256 -> 8x32) + BN + ELU -----
    gemm_bf16<<<dim3(4, (N_NODES + 127) / 128), 256, 0, stream>>>(obuf, wt2, hbuf, N_NODES, 256, 256);
    logits_blk<8, 1><<<(nh8 + 255) / 256, 256, 0, stream>>>(hbuf, as2, ad2, als, ald);
    gat_gather_blk<256, 8, true, true><<<BPG * 8, 256, 0, stream>>>(
        row_ptr, col, perm, hbuf, als, ald, b2, g2, be2, mn2, vr2, obuf);

    // ----- layer 3: GAT(256 -> 1x128), heads=1 (mean == identity) -----
    gemm_bf16<<<dim3(2, (N_NODES + 127) / 128), 256, 0, stream>>>(obuf, wt3, hbuf, N_NODES, 128, 256);
    logits_blk<1, 4><<<(N_NODES + 255) / 256, 256, 0, stream>>>(hbuf, as3, ad3, als, ald);
    gat_gather_blk<128, 1, false, false><<<BPG * 4, 256, 0, stream>>>(
        row_ptr, col, perm, hbuf, als, ald, b3, nullptr, nullptr, nullptr, nullptr, out);
}

// Round 8
// 578.281 us; speedup vs baseline: 1.4812x; 1.4812x over previous
//
#include <hip/hip_runtime.h>
#include <math.h>

#define N_NODES 50000
#define E_ORIG  800000
#define E_TOT   850000   // + self loops
#define SNB     49       // scan blocks: 49 * 1024 >= N_NODES
#define BPG     1563     // gather blocks per slice-phase: 1563 * 32 >= N_NODES

typedef __attribute__((ext_vector_type(8))) short short8;   // 8 bf16 (4 VGPRs)
typedef __attribute__((ext_vector_type(4))) float f32x4;    // MFMA acc

__device__ __forceinline__ short f2bf(float f) {            // fp32 -> bf16 RNE
    unsigned u = __builtin_bit_cast(unsigned, f);
    u += 0x7FFFu + ((u >> 16) & 1u);
    return (short)(u >> 16);
}
__device__ __forceinline__ float bf2f(short s) {
    unsigned u = ((unsigned)(unsigned short)s) << 16;
    return __builtin_bit_cast(float, u);
}

// ---------------- bf16 MFMA GEMM: C_t[blk][m][32] = (A[M,K] @ W[K,N]) sliced ----------------
// 128x64 tile (many blocks: these GEMMs are thin/tail-bound), BK=32, 4 waves = 2x2 of 64x32.
__global__ __launch_bounds__(256) void gemm_bf16(const short* __restrict__ A,
                                                 const short* __restrict__ Wt,   // W^T [N][K]
                                                 short* __restrict__ C,          // [N/32][N_NODES][32]
                                                 int M, int N, int K)
{
    __shared__ short sA[128][40];
    __shared__ short sB[64][40];
    const int t    = threadIdx.x;
    const int wave = t >> 6, lane = t & 63;
    const int quad = lane >> 4, mrow = lane & 15;
    const int m0 = blockIdx.y * 128, n0 = blockIdx.x * 64;
    const int wm = (wave & 1) * 64, wn = (wave >> 1) * 32;

    f32x4 acc[4][2] = {};

    const int ra = t >> 2, ka = (t & 3) << 3;   // A: 2 passes of 64 rows, 8 shorts each
    const int rb = t >> 2, kb = (t & 3) << 3;   // B: 64 rows, 8 shorts each

    for (int k0 = 0; k0 < K; k0 += 32) {
#pragma unroll
        for (int rr = 0; rr < 2; ++rr) {
            int row = ra + rr * 64;
            int gm = m0 + row;
            int4 v = {0, 0, 0, 0};
            if (gm < M) v = *(const int4*)(A + (size_t)gm * K + k0 + ka);
            *(int4*)&sA[row][ka] = v;
        }
        {
            int4 v = *(const int4*)(Wt + (size_t)(n0 + rb) * K + k0 + kb);
            *(int4*)&sB[rb][kb] = v;
        }
        __syncthreads();
        short8 af[4], bfr[2];
#pragma unroll
        for (int mi = 0; mi < 4; ++mi)
            af[mi] = *(const short8*)&sA[wm + mi * 16 + mrow][quad * 8];
#pragma unroll
        for (int ni = 0; ni < 2; ++ni)
            bfr[ni] = *(const short8*)&sB[wn + ni * 16 + mrow][quad * 8];
#pragma unroll
        for (int mi = 0; mi < 4; ++mi)
#pragma unroll
            for (int ni = 0; ni < 2; ++ni)
                acc[mi][ni] = __builtin_amdgcn_mfma_f32_16x16x32_bf16(af[mi], bfr[ni], acc[mi][ni], 0, 0, 0);
        __syncthreads();
    }
    // C/D layout: col = lane&15, row = quad*4 + reg; write slice-major
#pragma unroll
    for (int mi = 0; mi < 4; ++mi) {
#pragma unroll
        for (int ni = 0; ni < 2; ++ni) {
            int gn = n0 + wn + ni * 16 + mrow;
            size_t sbase = ((size_t)(gn >> 5) * N_NODES) * 32 + (gn & 31);
            int gmb = m0 + wm + mi * 16 + quad * 4;
#pragma unroll
            for (int r = 0; r < 4; ++r) {
                int gm = gmb + r;
                if (gm < M) C[sbase + (size_t)gm * 32] = f2bf(acc[mi][ni][r]);
            }
        }
    }
}

// ---------------- casts ----------------
__global__ void xcast_kernel(const float* __restrict__ x, short* __restrict__ xb, int total4)
{
    int i = blockIdx.x * blockDim.x + threadIdx.x;
    if (i >= total4) return;
    float4 v = ((const float4*)x)[i];
    short4 o; o.x = f2bf(v.x); o.y = f2bf(v.y); o.z = f2bf(v.z); o.w = f2bf(v.w);
    ((short4*)xb)[i] = o;
}

__global__ void wtcast_all(const float* __restrict__ W1, const float* __restrict__ W2,
                           const float* __restrict__ W3, short* __restrict__ wt)
{
    int i = blockIdx.x * blockDim.x + threadIdx.x;
    if (i < 32768) {                       // W1: K=128, N=256
        int n = i / 128, k = i % 128;
        wt[i] = f2bf(W1[(size_t)k * 256 + n]);
    } else if (i < 98304) {                // W2: K=256, N=256
        int j = i - 32768;
        int n = j / 256, k = j % 256;
        wt[i] = f2bf(W2[(size_t)k * 256 + n]);
    } else if (i < 131072) {               // W3: K=256, N=128
        int j = i - 98304;
        int n = j / 256, k = j % 256;
        wt[i] = f2bf(W3[(size_t)k * 128 + n]);
    }
}

// ---------------- attention logits, head-major outputs: al[h][n] ----------------
template<int H, int BPH>
__global__ void logits_blk(const short* __restrict__ ht,
                           const float* __restrict__ a_src,
                           const float* __restrict__ a_dst,
                           float* __restrict__ al_s, float* __restrict__ al_d)
{
    int i = blockIdx.x * blockDim.x + threadIdx.x;
    if (i >= N_NODES * H) return;
    int n = i / H, hh = i % H;
    float ss = 0.f, sd = 0.f;
#pragma unroll
    for (int b = 0; b < BPH; ++b) {
        int blk = hh * BPH + b;
        const short* hp = ht + ((size_t)blk * N_NODES + n) * 32;
        const float* as = a_src + blk * 32;
        const float* ad = a_dst + blk * 32;
#pragma unroll
        for (int c8 = 0; c8 < 32; c8 += 8) {
            short8 hv = *(const short8*)(hp + c8);
#pragma unroll
            for (int j = 0; j < 8; ++j) {
                float v = bf2f(hv[j]);
                ss = fmaf(v, as[c8 + j], ss);
                sd = fmaf(v, ad[c8 + j], sd);
            }
        }
    }
    al_s[(size_t)hh * N_NODES + n] = ss;
    al_d[(size_t)hh * N_NODES + n] = sd;
}

// ---------------- CSR build ----------------
__global__ void deg_kernel(const int* __restrict__ ei, int* __restrict__ deg)
{
    int e = blockIdx.x * blockDim.x + threadIdx.x;
    if (e >= E_TOT) return;
    int d = (e < E_ORIG) ? ei[E_ORIG + e] : e - E_ORIG;
    atomicAdd(&deg[d], 1);
}

__global__ __launch_bounds__(256) void scan_p1(const int* __restrict__ deg, int* __restrict__ bsum)
{
    __shared__ int wsum[4];
    int t = threadIdx.x;
    int base = blockIdx.x * 1024 + t * 4;
    int s = 0;
    if (base + 3 < N_NODES) {
        int4 v = *(const int4*)(deg + base);
        s = v.x + v.y + v.z + v.w;
    } else if (base < N_NODES) {
        for (int j = 0; j < 4 && base + j < N_NODES; ++j) s += deg[base + j];
    }
#pragma unroll
    for (int d = 32; d; d >>= 1) s += __shfl_down(s, d);
    if ((t & 63) == 0) wsum[t >> 6] = s;
    __syncthreads();
    if (t == 0) bsum[blockIdx.x] = wsum[0] + wsum[1] + wsum[2] + wsum[3];
}

__global__ void scan_p2(const int* __restrict__ bsum, int* __restrict__ bpre,
                        int* __restrict__ row_ptr)
{
    int t = threadIdx.x;   // 64 threads
    int v = (t < SNB) ? bsum[t] : 0;
    int inc = v;
#pragma unroll
    for (int d = 1; d < 64; d <<= 1) {
        int u = __shfl_up(inc, d);
        if (t >= d) inc += u;
    }
    if (t < SNB) bpre[t] = inc - v;
    if (t == SNB - 1) row_ptr[N_NODES] = inc;
}

__global__ __launch_bounds__(256) void scan_p3(const int* __restrict__ deg,
                                               const int* __restrict__ bpre,
                                               int* __restrict__ row_ptr,
                                               int* __restrict__ cursor)
{
    __shared__ int tsum[256];
    int t = threadIdx.x;
    int base = blockIdx.x * 1024 + t * 4;
    int d0 = 0, d1 = 0, d2 = 0, d3 = 0;
    if (base + 3 < N_NODES) {
        int4 v = *(const int4*)(deg + base);
        d0 = v.x; d1 = v.y; d2 = v.z; d3 = v.w;
    } else if (base < N_NODES) {
        d0 = deg[base];
        if (base + 1 < N_NODES) d1 = deg[base + 1];
        if (base + 2 < N_NODES) d2 = deg[base + 2];
    }
    int s = d0 + d1 + d2 + d3;
    tsum[t] = s;
    __syncthreads();
    for (int off = 1; off < 256; off <<= 1) {
        int u = (t >= off) ? tsum[t - off] : 0;
        __syncthreads();
        tsum[t] += u;
        __syncthreads();
    }
    int run = bpre[blockIdx.x] + tsum[t] - s;
    if (base < N_NODES)     { row_ptr[base]     = run; cursor[base]     = run; run += d0; }
    if (base + 1 < N_NODES) { row_ptr[base + 1] = run; cursor[base + 1] = run; run += d1; }
    if (base + 2 < N_NODES) { row_ptr[base + 2] = run; cursor[base + 2] = run; run += d2; }
    if (base + 3 < N_NODES) { row_ptr[base + 3] = run; cursor[base + 3] = run; }
}

__global__ void fill_kernel(const int* __restrict__ ei, int* __restrict__ cursor,
                            int* __restrict__ col)
{
    int e = blockIdx.x * blockDim.x + threadIdx.x;
    if (e >= E_TOT) return;
    int s, d;
    if (e < E_ORIG) { s = ei[e]; d = ei[E_ORIG + e]; } else { s = d = e - E_ORIG; }
    int pos = atomicAdd(&cursor[d], 1);
    col[pos] = s;
}

// ---------------- slice-blocked gather with fused softmax weight ----------------
// grid = NBLK slice-phases x BPG blocks; block = 32 nodes x 8 lanes (one 64B line per edge).
// w = exp(leaky(al_s[s]+al_d[n])) computed inline; al_s head-slice (200 KB) stays L2-hot.
template<int HC, int H, bool BN, bool OUTBF>
__global__ __launch_bounds__(256) void gat_gather_blk(const int* __restrict__ row_ptr,
                                                      const int* __restrict__ col,
                                                      const short* __restrict__ ht,
                                                      const float* __restrict__ al_s,
                                                      const float* __restrict__ al_d,
                                                      const float* __restrict__ bias,
                                                      const float* __restrict__ gamma,
                                                      const float* __restrict__ beta,
                                                      const float* __restrict__ mean,
                                                      const float* __restrict__ var,
                                                      void* __restrict__ outp)
{
    constexpr int NBLK = HC / 32;
    int blk  = blockIdx.x / BPG;
    int nb   = blockIdx.x % BPG;
    int n = nb * 32 + (threadIdx.x >> 3);
    if (n >= N_NODES) return;
    int lane  = threadIdx.x & 7;
    int head  = (blk * H) / NBLK;
    int c_loc = lane * 4;
    const short* hb  = ht + (size_t)blk * N_NODES * 32 + c_loc;
    const float* als = al_s + (size_t)head * N_NODES;
    float aldn = al_d[(size_t)head * N_NODES + n];
    int beg = row_ptr[n], end = row_ptr[n + 1];
    float a0 = 0.f, a1 = 0.f, a2 = 0.f, a3 = 0.f, den = 0.f;
    int e = beg;
#define MKW(si, wi) { float v = als[si] + aldn; v = v > 0.f ? v : 0.2f * v; wi = __expf(v); }
    for (; e + 3 < end; e += 4) {
        int s0 = col[e], s1 = col[e + 1], s2 = col[e + 2], s3 = col[e + 3];
        float w0, w1, w2, w3;
        MKW(s0, w0); MKW(s1, w1); MKW(s2, w2); MKW(s3, w3);
        short4 h0 = *(const short4*)(hb + (size_t)s0 * 32);
        short4 h1 = *(const short4*)(hb + (size_t)s1 * 32);
        short4 h2 = *(const short4*)(hb + (size_t)s2 * 32);
        short4 h3 = *(const short4*)(hb + (size_t)s3 * 32);
        den += (w0 + w1) + (w2 + w3);
        a0 = fmaf(w0, bf2f(h0.x), a0); a1 = fmaf(w0, bf2f(h0.y), a1);
        a2 = fmaf(w0, bf2f(h0.z), a2); a3 = fmaf(w0, bf2f(h0.w), a3);
        a0 = fmaf(w1, bf2f(h1.x), a0); a1 = fmaf(w1, bf2f(h1.y), a1);
        a2 = fmaf(w1, bf2f(h1.z), a2); a3 = fmaf(w1, bf2f(h1.w), a3);
        a0 = fmaf(w2, bf2f(h2.x), a0); a1 = fmaf(w2, bf2f(h2.y), a1);
        a2 = fmaf(w2, bf2f(h2.z), a2); a3 = fmaf(w2, bf2f(h2.w), a3);
        a0 = fmaf(w3, bf2f(h3.x), a0); a1 = fmaf(w3, bf2f(h3.y), a1);
        a2 = fmaf(w3, bf2f(h3.z), a2); a3 = fmaf(w3, bf2f(h3.w), a3);
    }
    for (; e < end; ++e) {
        int s0 = col[e];
        float w0; MKW(s0, w0);
        short4 h0 = *(const short4*)(hb + (size_t)s0 * 32);
        den += w0;
        a0 = fmaf(w0, bf2f(h0.x), a0); a1 = fmaf(w0, bf2f(h0.y), a1);
        a2 = fmaf(w0, bf2f(h0.z), a2); a3 = fmaf(w0, bf2f(h0.w), a3);
    }
#undef MKW
    float inv = 1.f / den;
    float r[4] = { a0 * inv, a1 * inv, a2 * inv, a3 * inv };
    int cb = blk * 32 + c_loc;
#pragma unroll
    for (int j = 0; j < 4; ++j) {
        int c = cb + j;
        float v = r[j] + bias[c];
        if (BN) {
            v = (v - mean[c]) * rsqrtf(var[c] + 1e-5f) * gamma[c] + beta[c];
            v = v > 0.f ? v : expm1f(v);   // ELU
        }
        r[j] = v;
    }
    if (OUTBF) {
        short4 o; o.x = f2bf(r[0]); o.y = f2bf(r[1]); o.z = f2bf(r[2]); o.w = f2bf(r[3]);
        *(short4*)((short*)outp + (size_t)n * HC + cb) = o;
    } else {
        *(float4*)((float*)outp + (size_t)n * HC + cb) = make_float4(r[0], r[1], r[2], r[3]);
    }
}

extern "C" void kernel_launch(void* const* d_in, const int* in_sizes, int n_in,
                              void* d_out, int out_size, void* d_ws, size_t ws_size,
                              hipStream_t stream)
{
    const float* x   = (const float*)d_in[0];
    const int*   ei  = (const int*)d_in[1];
    const float* W1  = (const float*)d_in[2];
    const float* as1 = (const float*)d_in[3];
    const float* ad1 = (const float*)d_in[4];
    const float* b1  = (const float*)d_in[5];
    const float* g1  = (const float*)d_in[6];
    const float* be1 = (const float*)d_in[7];
    const float* mn1 = (const float*)d_in[8];
    const float* vr1 = (const float*)d_in[9];
    const float* W2  = (const float*)d_in[10];
    const float* as2 = (const float*)d_in[11];
    const float* ad2 = (const float*)d_in[12];
    const float* b2  = (const float*)d_in[13];
    const float* g2  = (const float*)d_in[14];
    const float* be2 = (const float*)d_in[15];
    const float* mn2 = (const float*)d_in[16];
    const float* vr2 = (const float*)d_in[17];
    const float* W3  = (const float*)d_in[18];
    const float* as3 = (const float*)d_in[19];
    const float* ad3 = (const float*)d_in[20];
    const float* b3  = (const float*)d_in[21];

    char* p = (char*)d_ws;
    short* hbuf    = (short*)p; p += (size_t)N_NODES * 256 * 2;     // 25.6 MB (slice-major h)
    short* obuf    = (short*)p; p += (size_t)N_NODES * 256 * 2;     // 25.6 MB (row-major layer out)
    short* xbf     = (short*)p; p += (size_t)N_NODES * 128 * 2;     // 12.8 MB (bf16 x)
    short* wtbuf   = (short*)p; p += (size_t)131072 * 2;            // 256 KB (wt1|wt2|wt3)
    float* als     = (float*)p; p += (size_t)N_NODES * 8 * 4;       // head-major [h][n]
    float* ald     = (float*)p; p += (size_t)N_NODES * 8 * 4;
    int*   row_ptr = (int*)p;   p += (size_t)(N_NODES + 1) * 4;
    int*   col     = (int*)p;   p += (size_t)E_TOT * 4;
    int*   deg     = (int*)p;   p += (size_t)N_NODES * 4;
    int*   cursor  = (int*)p;   p += (size_t)N_NODES * 4;
    int*   bsum    = (int*)p;   p += 64 * 4;
    int*   bpre    = (int*)p;   p += 64 * 4;

    short* wt1 = wtbuf;           // [256][128]
    short* wt2 = wtbuf + 32768;   // [256][256]
    short* wt3 = wtbuf + 98304;   // [128][256]

    float* out = (float*)d_out;

    // ----- CSR build + upfront casts -----
    hipMemsetAsync(deg, 0, (size_t)N_NODES * 4, stream);
    deg_kernel<<<(E_TOT + 255) / 256, 256, 0, stream>>>(ei, deg);
    scan_p1<<<SNB, 256, 0, stream>>>(deg, bsum);
    scan_p2<<<1, 64, 0, stream>>>(bsum, bpre, row_ptr);
    scan_p3<<<SNB, 256, 0, stream>>>(deg, bpre, row_ptr, cursor);
    fill_kernel<<<(E_TOT + 255) / 256, 256, 0, stream>>>(ei, cursor, col);
    xcast_kernel<<<(N_NODES * 128 / 4 + 255) / 256, 256, 0, stream>>>(x, xbf, N_NODES * 128 / 4);
    wtcast_all<<<(131072 + 255) / 256, 256, 0, stream>>>(W1, W2, W3, wtbuf);

    const int nh8 = N_NODES * 8;

    // ----- layer 1: GAT(128 -> 8x32) + BN + ELU -----
    gemm_bf16<<<dim3(4, (N_NODES + 127) / 128), 256, 0, stream>>>(xbf, wt1, hbuf, N_NODES, 256, 128);
    logits_blk<8, 1><<<(nh8 + 255) / 256, 256, 0, stream>>>(hbuf, as1, ad1, als, ald);
    gat_gather_blk<256, 8, true, true><<<BPG * 8, 256, 0, stream>>>(
        row_ptr, col, hbuf, als, ald, b1, g1, be1, mn1, vr1, obuf);

    // ----- layer 2: GAT(256 -> 8x32) + BN + ELU -----
    gemm_bf16<<<dim3(4, (N_NODES + 127) / 128), 256, 0, stream>>>(obuf, wt2, hbuf, N_NODES, 256, 256);
    logits_blk<8, 1><<<(nh8 + 255) / 256, 256, 0, stream>>>(hbuf, as2, ad2, als, ald);
    gat_gather_blk<256, 8, true, true><<<BPG * 8, 256, 0, stream>>>(
        row_ptr, col, hbuf, als, ald, b2, g2, be2, mn2, vr2, obuf);

    // ----- layer 3: GAT(256 -> 1x128), heads=1 (mean == identity) -----
    gemm_bf16<<<dim3(2, (N_NODES + 127) / 128), 256, 0, stream>>>(obuf, wt3, hbuf, N_NODES, 128, 256);
    logits_blk<1, 4><<<(N_NODES + 255) / 256, 256, 0, stream>>>(hbuf, as3, ad3, als, ald);
    gat_gather_blk<128, 1, false, false><<<BPG * 4, 256, 0, stream>>>(
        row_ptr, col, hbuf, als, ald, b3, nullptr, nullptr, nullptr, nullptr, out);
}

// Round 9
// 559.639 us; speedup vs baseline: 1.5305x; 1.0333x over previous
//
#include <hip/hip_runtime.h>
#include <math.h>

#define N_NODES 50000
#define E_ORIG  800000
#define E_TOT   850000   // + self loops
#define SNB     49       // scan blocks: 49 * 1024 >= N_NODES
#define BPG     1563     // gather node-blocks per slice: 1563 * 32 >= N_NODES

typedef __attribute__((ext_vector_type(8))) short short8;   // 8 bf16 (4 VGPRs)
typedef __attribute__((ext_vector_type(4))) float f32x4;    // MFMA acc

__device__ __forceinline__ short f2bf(float f) {            // fp32 -> bf16 RNE
    unsigned u = __builtin_bit_cast(unsigned, f);
    u += 0x7FFFu + ((u >> 16) & 1u);
    return (short)(u >> 16);
}
__device__ __forceinline__ float bf2f(short s) {
    unsigned u = ((unsigned)(unsigned short)s) << 16;
    return __builtin_bit_cast(float, u);
}

// ---------------- bf16 MFMA GEMM: C_t[blk][m][32] = (A[M,K] @ W[K,N]) sliced ----------------
// 128x64 tile, BK=32, 4 waves = 2x2 of 64x32.
__global__ __launch_bounds__(256) void gemm_bf16(const short* __restrict__ A,
                                                 const short* __restrict__ Wt,   // W^T [N][K]
                                                 short* __restrict__ C,          // [N/32][N_NODES][32]
                                                 int M, int N, int K)
{
    __shared__ short sA[128][40];
    __shared__ short sB[64][40];
    const int t    = threadIdx.x;
    const int wave = t >> 6, lane = t & 63;
    const int quad = lane >> 4, mrow = lane & 15;
    const int m0 = blockIdx.y * 128, n0 = blockIdx.x * 64;
    const int wm = (wave & 1) * 64, wn = (wave >> 1) * 32;

    f32x4 acc[4][2] = {};

    const int ra = t >> 2, ka = (t & 3) << 3;   // A: 2 passes of 64 rows, 8 shorts each
    const int rb = t >> 2, kb = (t & 3) << 3;   // B: 64 rows, 8 shorts each

    for (int k0 = 0; k0 < K; k0 += 32) {
#pragma unroll
        for (int rr = 0; rr < 2; ++rr) {
            int row = ra + rr * 64;
            int gm = m0 + row;
            int4 v = {0, 0, 0, 0};
            if (gm < M) v = *(const int4*)(A + (size_t)gm * K + k0 + ka);
            *(int4*)&sA[row][ka] = v;
        }
        {
            int4 v = *(const int4*)(Wt + (size_t)(n0 + rb) * K + k0 + kb);
            *(int4*)&sB[rb][kb] = v;
        }
        __syncthreads();
        short8 af[4], bfr[2];
#pragma unroll
        for (int mi = 0; mi < 4; ++mi)
            af[mi] = *(const short8*)&sA[wm + mi * 16 + mrow][quad * 8];
#pragma unroll
        for (int ni = 0; ni < 2; ++ni)
            bfr[ni] = *(const short8*)&sB[wn + ni * 16 + mrow][quad * 8];
#pragma unroll
        for (int mi = 0; mi < 4; ++mi)
#pragma unroll
            for (int ni = 0; ni < 2; ++ni)
                acc[mi][ni] = __builtin_amdgcn_mfma_f32_16x16x32_bf16(af[mi], bfr[ni], acc[mi][ni], 0, 0, 0);
        __syncthreads();
    }
    // C/D layout: col = lane&15, row = quad*4 + reg; write slice-major
#pragma unroll
    for (int mi = 0; mi < 4; ++mi) {
#pragma unroll
        for (int ni = 0; ni < 2; ++ni) {
            int gn = n0 + wn + ni * 16 + mrow;
            size_t sbase = ((size_t)(gn >> 5) * N_NODES) * 32 + (gn & 31);
            int gmb = m0 + wm + mi * 16 + quad * 4;
#pragma unroll
            for (int r = 0; r < 4; ++r) {
                int gm = gmb + r;
                if (gm < M) C[sbase + (size_t)gm * 32] = f2bf(acc[mi][ni][r]);
            }
        }
    }
}

// ---------------- casts ----------------
__global__ void xcast_kernel(const float* __restrict__ x, short* __restrict__ xb, int total4)
{
    int i = blockIdx.x * blockDim.x + threadIdx.x;
    if (i >= total4) return;
    float4 v = ((const float4*)x)[i];
    short4 o; o.x = f2bf(v.x); o.y = f2bf(v.y); o.z = f2bf(v.z); o.w = f2bf(v.w);
    ((short4*)xb)[i] = o;
}

__global__ void wtcast_all(const float* __restrict__ W1, const float* __restrict__ W2,
                           const float* __restrict__ W3, short* __restrict__ wt)
{
    int i = blockIdx.x * blockDim.x + threadIdx.x;
    if (i < 32768) {                       // W1: K=128, N=256
        int n = i / 128, k = i % 128;
        wt[i] = f2bf(W1[(size_t)k * 256 + n]);
    } else if (i < 98304) {                // W2: K=256, N=256
        int j = i - 32768;
        int n = j / 256, k = j % 256;
        wt[i] = f2bf(W2[(size_t)k * 256 + n]);
    } else if (i < 131072) {               // W3: K=256, N=128
        int j = i - 98304;
        int n = j / 256, k = j % 256;
        wt[i] = f2bf(W3[(size_t)k * 128 + n]);
    }
}

// ---------------- attention logits, head-major outputs: al[h][n] ----------------
template<int H, int BPH>
__global__ void logits_blk(const short* __restrict__ ht,
                           const float* __restrict__ a_src,
                           const float* __restrict__ a_dst,
                           float* __restrict__ al_s, float* __restrict__ al_d)
{
    int i = blockIdx.x * blockDim.x + threadIdx.x;
    if (i >= N_NODES * H) return;
    int n = i / H, hh = i % H;
    float ss = 0.f, sd = 0.f;
#pragma unroll
    for (int b = 0; b < BPH; ++b) {
        int blk = hh * BPH + b;
        const short* hp = ht + ((size_t)blk * N_NODES + n) * 32;
        const float* as = a_src + blk * 32;
        const float* ad = a_dst + blk * 32;
#pragma unroll
        for (int c8 = 0; c8 < 32; c8 += 8) {
            short8 hv = *(const short8*)(hp + c8);
#pragma unroll
            for (int j = 0; j < 8; ++j) {
                float v = bf2f(hv[j]);
                ss = fmaf(v, as[c8 + j], ss);
                sd = fmaf(v, ad[c8 + j], sd);
            }
        }
    }
    al_s[(size_t)hh * N_NODES + n] = ss;
    al_d[(size_t)hh * N_NODES + n] = sd;
}

// ---------------- CSR build ----------------
__global__ void deg_kernel(const int* __restrict__ ei, int* __restrict__ deg)
{
    int e = blockIdx.x * blockDim.x + threadIdx.x;
    if (e >= E_TOT) return;
    int d = (e < E_ORIG) ? ei[E_ORIG + e] : e - E_ORIG;
    atomicAdd(&deg[d], 1);
}

__global__ __launch_bounds__(256) void scan_p1(const int* __restrict__ deg, int* __restrict__ bsum)
{
    __shared__ int wsum[4];
    int t = threadIdx.x;
    int base = blockIdx.x * 1024 + t * 4;
    int s = 0;
    if (base + 3 < N_NODES) {
        int4 v = *(const int4*)(deg + base);
        s = v.x + v.y + v.z + v.w;
    } else if (base < N_NODES) {
        for (int j = 0; j < 4 && base + j < N_NODES; ++j) s += deg[base + j];
    }
#pragma unroll
    for (int d = 32; d; d >>= 1) s += __shfl_down(s, d);
    if ((t & 63) == 0) wsum[t >> 6] = s;
    __syncthreads();
    if (t == 0) bsum[blockIdx.x] = wsum[0] + wsum[1] + wsum[2] + wsum[3];
}

__global__ void scan_p2(const int* __restrict__ bsum, int* __restrict__ bpre,
                        int* __restrict__ row_ptr)
{
    int t = threadIdx.x;   // 64 threads
    int v = (t < SNB) ? bsum[t] : 0;
    int inc = v;
#pragma unroll
    for (int d = 1; d < 64; d <<= 1) {
        int u = __shfl_up(inc, d);
        if (t >= d) inc += u;
    }
    if (t < SNB) bpre[t] = inc - v;
    if (t == SNB - 1) row_ptr[N_NODES] = inc;
}

__global__ __launch_bounds__(256) void scan_p3(const int* __restrict__ deg,
                                               const int* __restrict__ bpre,
                                               int* __restrict__ row_ptr,
                                               int* __restrict__ cursor)
{
    __shared__ int tsum[256];
    int t = threadIdx.x;
    int base = blockIdx.x * 1024 + t * 4;
    int d0 = 0, d1 = 0, d2 = 0, d3 = 0;
    if (base + 3 < N_NODES) {
        int4 v = *(const int4*)(deg + base);
        d0 = v.x; d1 = v.y; d2 = v.z; d3 = v.w;
    } else if (base < N_NODES) {
        d0 = deg[base];
        if (base + 1 < N_NODES) d1 = deg[base + 1];
        if (base + 2 < N_NODES) d2 = deg[base + 2];
    }
    int s = d0 + d1 + d2 + d3;
    tsum[t] = s;
    __syncthreads();
    for (int off = 1; off < 256; off <<= 1) {
        int u = (t >= off) ? tsum[t - off] : 0;
        __syncthreads();
        tsum[t] += u;
        __syncthreads();
    }
    int run = bpre[blockIdx.x] + tsum[t] - s;
    if (base < N_NODES)     { row_ptr[base]     = run; cursor[base]     = run; run += d0; }
    if (base + 1 < N_NODES) { row_ptr[base + 1] = run; cursor[base + 1] = run; run += d1; }
    if (base + 2 < N_NODES) { row_ptr[base + 2] = run; cursor[base + 2] = run; run += d2; }
    if (base + 3 < N_NODES) { row_ptr[base + 3] = run; cursor[base + 3] = run; }
}

__global__ void fill_kernel(const int* __restrict__ ei, int* __restrict__ cursor,
                            int* __restrict__ col)
{
    int e = blockIdx.x * blockDim.x + threadIdx.x;
    if (e >= E_TOT) return;
    int s, d;
    if (e < E_ORIG) { s = ei[e]; d = ei[E_ORIG + e]; } else { s = d = e - E_ORIG; }
    int pos = atomicAdd(&cursor[d], 1);
    col[pos] = s;
}

// ---------------- slice-blocked gather, XCD-pinned ----------------
// slice = blockIdx.x % NBLK, node-range = blockIdx.x / NBLK. On MI355X consecutive
// workgroups round-robin across the 8 XCDs, so (for NBLK=8) all blocks of slice s
// land on XCD s: each XCD's L2 caches only its own 3.2 MB slice -> no 8x replication.
// w = exp(leaky(al_s[s]+al_d[n])) fused; al_s head-table (200 KB) is XCD-resident.
template<int HC, int H, bool BN, bool OUTBF>
__global__ __launch_bounds__(256) void gat_gather_blk(const int* __restrict__ row_ptr,
                                                      const int* __restrict__ col,
                                                      const short* __restrict__ ht,
                                                      const float* __restrict__ al_s,
                                                      const float* __restrict__ al_d,
                                                      const float* __restrict__ bias,
                                                      const float* __restrict__ gamma,
                                                      const float* __restrict__ beta,
                                                      const float* __restrict__ mean,
                                                      const float* __restrict__ var,
                                                      void* __restrict__ outp)
{
    constexpr int NBLK = HC / 32;
    int blk  = blockIdx.x % NBLK;        // slice id == XCD id (mod 8)
    int nb   = blockIdx.x / NBLK;
    int n = nb * 32 + (threadIdx.x >> 3);
    if (n >= N_NODES) return;
    int lane  = threadIdx.x & 7;
    int head  = (blk * H) / NBLK;
    int c_loc = lane * 4;
    const short* hb  = ht + (size_t)blk * N_NODES * 32 + c_loc;
    const float* als = al_s + (size_t)head * N_NODES;
    float aldn = al_d[(size_t)head * N_NODES + n];
    int beg = row_ptr[n], end = row_ptr[n + 1];
    float a0 = 0.f, a1 = 0.f, a2 = 0.f, a3 = 0.f, den = 0.f;
    int e = beg;
#define MKW(si, wi) { float v = als[si] + aldn; v = v > 0.f ? v : 0.2f * v; wi = __expf(v); }
    for (; e + 3 < end; e += 4) {
        int s0 = col[e], s1 = col[e + 1], s2 = col[e + 2], s3 = col[e + 3];
        float w0, w1, w2, w3;
        MKW(s0, w0); MKW(s1, w1); MKW(s2, w2); MKW(s3, w3);
        short4 h0 = *(const short4*)(hb + (size_t)s0 * 32);
        short4 h1 = *(const short4*)(hb + (size_t)s1 * 32);
        short4 h2 = *(const short4*)(hb + (size_t)s2 * 32);
        short4 h3 = *(const short4*)(hb + (size_t)s3 * 32);
        den += (w0 + w1) + (w2 + w3);
        a0 = fmaf(w0, bf2f(h0.x), a0); a1 = fmaf(w0, bf2f(h0.y), a1);
        a2 = fmaf(w0, bf2f(h0.z), a2); a3 = fmaf(w0, bf2f(h0.w), a3);
        a0 = fmaf(w1, bf2f(h1.x), a0); a1 = fmaf(w1, bf2f(h1.y), a1);
        a2 = fmaf(w1, bf2f(h1.z), a2); a3 = fmaf(w1, bf2f(h1.w), a3);
        a0 = fmaf(w2, bf2f(h2.x), a0); a1 = fmaf(w2, bf2f(h2.y), a1);
        a2 = fmaf(w2, bf2f(h2.z), a2); a3 = fmaf(w2, bf2f(h2.w), a3);
        a0 = fmaf(w3, bf2f(h3.x), a0); a1 = fmaf(w3, bf2f(h3.y), a1);
        a2 = fmaf(w3, bf2f(h3.z), a2); a3 = fmaf(w3, bf2f(h3.w), a3);
    }
    for (; e < end; ++e) {
        int s0 = col[e];
        float w0; MKW(s0, w0);
        short4 h0 = *(const short4*)(hb + (size_t)s0 * 32);
        den += w0;
        a0 = fmaf(w0, bf2f(h0.x), a0); a1 = fmaf(w0, bf2f(h0.y), a1);
        a2 = fmaf(w0, bf2f(h0.z), a2); a3 = fmaf(w0, bf2f(h0.w), a3);
    }
#undef MKW
    float inv = 1.f / den;
    float r[4] = { a0 * inv, a1 * inv, a2 * inv, a3 * inv };
    int cb = blk * 32 + c_loc;
#pragma unroll
    for (int j = 0; j < 4; ++j) {
        int c = cb + j;
        float v = r[j] + bias[c];
        if (BN) {
            v = (v - mean[c]) * rsqrtf(var[c] + 1e-5f) * gamma[c] + beta[c];
            v = v > 0.f ? v : expm1f(v);   // ELU
        }
        r[j] = v;
    }
    if (OUTBF) {
        short4 o; o.x = f2bf(r[0]); o.y = f2bf(r[1]); o.z = f2bf(r[2]); o.w = f2bf(r[3]);
        *(short4*)((short*)outp + (size_t)n * HC + cb) = o;
    } else {
        *(float4*)((float*)outp + (size_t)n * HC + cb) = make_float4(r[0], r[1], r[2], r[3]);
    }
}

extern "C" void kernel_launch(void* const* d_in, const int* in_sizes, int n_in,
                              void* d_out, int out_size, void* d_ws, size_t ws_size,
                              hipStream_t stream)
{
    const float* x   = (const float*)d_in[0];
    const int*   ei  = (const int*)d_in[1];
    const float* W1  = (const float*)d_in[2];
    const float* as1 = (const float*)d_in[3];
    const float* ad1 = (const float*)d_in[4];
    const float* b1  = (const float*)d_in[5];
    const float* g1  = (const float*)d_in[6];
    const float* be1 = (const float*)d_in[7];
    const float* mn1 = (const float*)d_in[8];
    const float* vr1 = (const float*)d_in[9];
    const float* W2  = (const float*)d_in[10];
    const float* as2 = (const float*)d_in[11];
    const float* ad2 = (const float*)d_in[12];
    const float* b2  = (const float*)d_in[13];
    const float* g2  = (const float*)d_in[14];
    const float* be2 = (const float*)d_in[15];
    const float* mn2 = (const float*)d_in[16];
    const float* vr2 = (const float*)d_in[17];
    const float* W3  = (const float*)d_in[18];
    const float* as3 = (const float*)d_in[19];
    const float* ad3 = (const float*)d_in[20];
    const float* b3  = (const float*)d_in[21];

    char* p = (char*)d_ws;
    short* hbuf    = (short*)p; p += (size_t)N_NODES * 256 * 2;     // 25.6 MB (slice-major h)
    short* obuf    = (short*)p; p += (size_t)N_NODES * 256 * 2;     // 25.6 MB (row-major layer out)
    short* xbf     = (short*)p; p += (size_t)N_NODES * 128 * 2;     // 12.8 MB (bf16 x)
    short* wtbuf   = (short*)p; p += (size_t)131072 * 2;            // 256 KB (wt1|wt2|wt3)
    float* als     = (float*)p; p += (size_t)N_NODES * 8 * 4;       // head-major [h][n]
    float* ald     = (float*)p; p += (size_t)N_NODES * 8 * 4;
    int*   row_ptr = (int*)p;   p += (size_t)(N_NODES + 1) * 4;
    int*   col     = (int*)p;   p += (size_t)E_TOT * 4;
    int*   deg     = (int*)p;   p += (size_t)N_NODES * 4;
    int*   cursor  = (int*)p;   p += (size_t)N_NODES * 4;
    int*   bsum    = (int*)p;   p += 64 * 4;
    int*   bpre    = (int*)p;   p += 64 * 4;

    short* wt1 = wtbuf;           // [256][128]
    short* wt2 = wtbuf + 32768;   // [256][256]
    short* wt3 = wtbuf + 98304;   // [128][256]

    float* out = (float*)d_out;

    // ----- CSR build + upfront casts -----
    hipMemsetAsync(deg, 0, (size_t)N_NODES * 4, stream);
    deg_kernel<<<(E_TOT + 255) / 256, 256, 0, stream>>>(ei, deg);
    scan_p1<<<SNB, 256, 0, stream>>>(deg, bsum);
    scan_p2<<<1, 64, 0, stream>>>(bsum, bpre, row_ptr);
    scan_p3<<<SNB, 256, 0, stream>>>(deg, bpre, row_ptr, cursor);
    fill_kernel<<<(E_TOT + 255) / 256, 256, 0, stream>>>(ei, cursor, col);
    xcast_kernel<<<(N_NODES * 128 / 4 + 255) / 256, 256, 0, stream>>>(x, xbf, N_NODES * 128 / 4);
    wtcast_all<<<(131072 + 255) / 256, 256, 0, stream>>>(W1, W2, W3, wtbuf);

    const int nh8 = N_NODES * 8;

    // ----- layer 1: GAT(128 -> 8x32) + BN + ELU -----
    gemm_bf16<<<dim3(4, (N_NODES + 127) / 128), 256, 0, stream>>>(xbf, wt1, hbuf, N_NODES, 256, 128);
    logits_blk<8, 1><<<(nh8 + 255) / 256, 256, 0, stream>>>(hbuf, as1, ad1, als, ald);
    gat_gather_blk<256, 8, true, true><<<BPG * 8, 256, 0, stream>>>(
        row_ptr, col, hbuf, als, ald, b1, g1, be1, mn1, vr1, obuf);

    // ----- layer 2: GAT(256 -> 8x32) + BN + ELU -----
    gemm_bf16<<<dim3(4, (N_NODES + 127) / 128), 256, 0, stream>>>(obuf, wt2, hbuf, N_NODES, 256, 256);
    logits_blk<8, 1><<<(nh8 + 255) / 256, 256, 0, stream>>>(hbuf, as2, ad2, als, ald);
    gat_gather_blk<256, 8, true, true><<<BPG * 8, 256, 0, stream>>>(
        row_ptr, col, hbuf, als, ald, b2, g2, be2, mn2, vr2, obuf);

    // ----- layer 3: GAT(256 -> 1x128), heads=1 (mean == identity) -----
    gemm_bf16<<<dim3(2, (N_NODES + 127) / 128), 256, 0, stream>>>(obuf, wt3, hbuf, N_NODES, 128, 256);
    logits_blk<1, 4><<<(N_NODES + 255) / 256, 256, 0, stream>>>(hbuf, as3, ad3, als, ald);
    gat_gather_blk<128, 1, false, false><<<BPG * 4, 256, 0, stream>>>(
        row_ptr, col, hbuf, als, ald, b3, nullptr, nullptr, nullptr, nullptr, out);
}